// Round 6
// baseline (318.301 us; speedup 1.0000x reference)
//
#include <hip/hip_runtime.h>

#define HH 1024
#define INW 512
#define BB 32
#define Z_MIN_C 0.001f
#define Z_RANGE_C 0.099f
#define E_H_C 0.5f

typedef float v4f __attribute__((ext_vector_type(4)));

__device__ __forceinline__ float sigmoidf_(float v) {
    return 1.0f / (1.0f + __expf(-v));
}

// ---------------- Kernel A: pre0[b,j] = (p @ x)[j,b] + bias[j] ----------------
// One wave per j-row. lane = (b = lane&31, half = lane>>5).
__global__ __launch_bounds__(256) void px_kernel(
    const float* __restrict__ x,    // (IN, B)
    const float* __restrict__ p,    // (H, IN)
    const float* __restrict__ bias, // (H, 1)
    float* __restrict__ pre0)       // (B, H) in workspace
{
    const int wv = threadIdx.x >> 6;
    const int lane = threadIdx.x & 63;
    const int j = blockIdx.x * 4 + wv;
    const int b = lane & 31;
    const int half = lane >> 5;

    const float* pr = p + j * INW + half * 256;
    const float* xc = x + (half * 256) * BB + b;
    float acc = 0.0f;
    #pragma unroll 8
    for (int i = 0; i < 256; ++i)
        acc = fmaf(pr[i], xc[i * BB], acc);
    acc += __shfl_xor(acc, 32);
    if (lane < 32)
        pre0[lane * HH + j] = acc + bias[j];
}

// ---------------- Kernel B: one block per (b,j) row ----------------
// 32768 tiny blocks (128 queued per CU): block-level interleaving keeps the
// memory system saturated (the fillBuffer regime: 87% peak at 10% occupancy).
// bid = b*1024 + j  =>  X/U accessed as one linear 4 KB chunk per block, a
// perfect sweep in dispatch order; the 32 blocks sharing param row j are
// bid==j (mod 1024) => same XCD => c_x/c_u/c_U/w rows L2-hot (2 MB/XCD).
// out/h/pre0 flat index == bid. One shuffle chain, 16 B LDS, 1-thread tail.
__global__ __launch_bounds__(256, 4) void stp_fused(
    const float* __restrict__ h,    // (B, H)
    const float* __restrict__ X,    // (B, H, H)
    const float* __restrict__ U,    // (B, H, H)
    const float* __restrict__ c_x,  // (H, H)
    const float* __restrict__ c_u,  // (H, H)
    const float* __restrict__ c_U,  // (H, H)
    const float* __restrict__ c_h,  // (H, 1)
    const float* __restrict__ w,    // (H, H)
    const float* __restrict__ pre0, // (B, H) workspace from px_kernel
    float* __restrict__ out)        // (B, H)
{
    const int bid = blockIdx.x;
    const int j = bid & (HH - 1);
    const int b = bid >> 10;
    const int t = threadIdx.x;
    const int lane = t & 63;
    const int wave = t >> 6;
    const int k0 = t * 4;

    __shared__ float rec_part[4];

    // ---- post the streaming loads first (X,U row chunk = read-once) ----
    const int rowbase = bid * HH;           // (b*HH + j)*HH / HH ... flat: bid*1024
    v4f Xv = __builtin_nontemporal_load((const v4f*)(X + rowbase + k0));
    v4f Uv = __builtin_nontemporal_load((const v4f*)(U + rowbase + k0));
    v4f hk = *(const v4f*)(h + b * HH + k0);
    const float hjv = h[bid];               // same addr across block -> broadcast
    const float pv = pre0[bid];             // prefetched for the tail
    const float chj = c_h[j];

    // ---- param loads (L2-hot) issue under the X/U flight ----
    v4f cx4 = *(const v4f*)(c_x + j * HH + k0);
    v4f cu4 = *(const v4f*)(c_u + j * HH + k0);
    v4f cC4 = *(const v4f*)(c_U + j * HH + k0);
    v4f wv4 = *(const v4f*)(w + j * HH + k0);

    float ss = 0.0f;
    #pragma unroll
    for (int c = 0; c < 4; ++c) {
        const float zxx = Z_MIN_C + Z_RANGE_C * sigmoidf_(cx4[c]);
        const float zuu = Z_MIN_C + Z_RANGE_C * sigmoidf_(cu4[c]);
        const float ucc = 0.9f * sigmoidf_(cC4[c]);
        const float uh = ucc * hjv;
        // U_new = ucc*zuu + (1-zuu)*U + uh*(1-U)  =  (ucc*zuu+uh) + (1-zuu-uh)*U
        const float t2 = fmaf(ucc, zuu, uh);
        const float t1 = (1.0f - zuu) - uh;
        float Un = fmaf(t1, Uv[c], t2);
        Un = fminf(fmaxf(Un, ucc), 1.0f);
        // X_new = zxx + (1-zxx)*X - U*(X*hjv)
        float Xn = fmaf(1.0f - zxx, Xv[c], zxx);
        Xn = fmaf(-Uv[c], Xv[c] * hjv, Xn);
        // rec contribution
        ss = fmaf(wv4[c] * hk[c], Un * Xn, ss);
    }

    // ---- single cross-lane reduction ----
    #pragma unroll
    for (int off = 32; off > 0; off >>= 1)
        ss += __shfl_xor(ss, off);
    if (lane == 0) rec_part[wave] = ss;
    __syncthreads();

    // ---- finalize (sole owner of (b,j)) ----
    if (t == 0) {
        const float rec = rec_part[0] + rec_part[1] + rec_part[2] + rec_part[3];
        const float pre = pv + rec;
        const float zh = E_H_C * sigmoidf_(chj);
        out[bid] = (1.0f - zh) * hjv + zh * sigmoidf_(pre);
    }
}

extern "C" void kernel_launch(void* const* d_in, const int* in_sizes, int n_in,
                              void* d_out, int out_size, void* d_ws, size_t ws_size,
                              hipStream_t stream) {
    const float* x   = (const float*)d_in[0];
    const float* h   = (const float*)d_in[1];
    const float* X   = (const float*)d_in[2];
    const float* U   = (const float*)d_in[3];
    const float* c_x = (const float*)d_in[4];
    const float* c_u = (const float*)d_in[5];
    const float* c_U = (const float*)d_in[6];
    const float* c_h = (const float*)d_in[7];
    const float* w   = (const float*)d_in[8];
    const float* p   = (const float*)d_in[9];
    const float* b   = (const float*)d_in[10];
    float* out = (float*)d_out;
    float* pre0 = (float*)d_ws;          // 32*1024 floats = 128 KB

    px_kernel<<<HH / 4, 256, 0, stream>>>(x, p, b, pre0);
    stp_fused<<<BB * HH, 256, 0, stream>>>(h, X, U, c_x, c_u, c_U, c_h, w, pre0, out);
}